// Round 1
// baseline (714.810 us; speedup 1.0000x reference)
//
#include <hip/hip_runtime.h>

typedef unsigned short u16;
typedef __attribute__((ext_vector_type(4))) unsigned short us4;
typedef __attribute__((ext_vector_type(4))) float f4;
typedef __attribute__((ext_vector_type(8))) short bf16x8;
typedef __attribute__((ext_vector_type(4))) float f32x4;

__device__ __forceinline__ u16 f2bf(float x) {
  unsigned u = __float_as_uint(x);
  return (u16)((u + 0x7FFFu + ((u >> 16) & 1u)) >> 16);
}
__device__ __forceinline__ float b2f(u16 s) {
  return __uint_as_float(((unsigned)s) << 16);
}
__device__ __forceinline__ float sigm(float x) { return 1.f / (1.f + __expf(-x)); }
__device__ __forceinline__ float tanhf_(float x) { return 2.f / (1.f + __expf(-2.f * x)) - 1.f; }

// ---------------------------------------------------------------------------
// Setup kernel 1: convert W_i..W_f, U_i..U_f (fp32 [1024][1024]) to bf16,
// packed gate-major: Wb[g][row][k], Ub[g][row][k].
// grid: 8192 blocks x 256 thr; 1024 blocks per matrix (1M elems each).
// ---------------------------------------------------------------------------
__global__ void convert_wu_kernel(const float* __restrict__ w0, const float* __restrict__ w1,
                                  const float* __restrict__ w2, const float* __restrict__ w3,
                                  const float* __restrict__ u0, const float* __restrict__ u1,
                                  const float* __restrict__ u2, const float* __restrict__ u3,
                                  u16* __restrict__ Wb, u16* __restrict__ Ub) {
  int mat = blockIdx.x >> 10;
  int off4 = (int)(blockIdx.x & 1023) * 256 + threadIdx.x;  // float4 index in matrix
  const float* src; u16* dst;
  switch (mat) {
    case 0: src = w0; dst = Wb; break;
    case 1: src = w1; dst = Wb + 1048576; break;
    case 2: src = w2; dst = Wb + 2097152; break;
    case 3: src = w3; dst = Wb + 3145728; break;
    case 4: src = u0; dst = Ub; break;
    case 5: src = u1; dst = Ub + 1048576; break;
    case 6: src = u2; dst = Ub + 2097152; break;
    default: src = u3; dst = Ub + 3145728; break;
  }
  f4 v = ((const f4*)src)[off4];
  us4 o = {f2bf(v[0]), f2bf(v[1]), f2bf(v[2]), f2bf(v[3])};
  ((us4*)dst)[off4] = o;
}

// ---------------------------------------------------------------------------
// Setup kernel 2: Xleaf[n][k] = bf16(tokens[leaf_ids[n]][k]). grid 8192 x 256.
// ---------------------------------------------------------------------------
__global__ void gather_leaf_kernel(const float* __restrict__ tokens,
                                   const int* __restrict__ ids, u16* __restrict__ Xl) {
  int n = blockIdx.x, t = threadIdx.x;
  int tok = ids[n];
  f4 v = ((const f4*)(tokens + (size_t)tok * 1024))[t];
  us4 o = {f2bf(v[0]), f2bf(v[1]), f2bf(v[2]), f2bf(v[3])};
  ((us4*)(Xl + (size_t)n * 1024))[t] = o;
}

// ---------------------------------------------------------------------------
// Setup kernel 3 (fp32 dots, tiny):
//   xw[op][g][j]   = op_emb[op] . W_g[j] + b_g[j]          (16384 outputs)
//   leafC[0..2][j] = (h_init0+h_init1) . U_g[j] + b_g[j]   (g = i,o,u)
//   leafC[3+k][j]  = h_init[k] . U_f[j] + b_f[j]           (k = 0,1)
// grid 84 x 256 (21504 outputs). Selection is uniform per block.
// ---------------------------------------------------------------------------
__global__ void precompute_kernel(const float* __restrict__ op_emb,
    const float* __restrict__ w0, const float* __restrict__ w1,
    const float* __restrict__ w2, const float* __restrict__ w3,
    const float* __restrict__ u0, const float* __restrict__ u1,
    const float* __restrict__ u2, const float* __restrict__ u3,
    const float* __restrict__ b0, const float* __restrict__ b1,
    const float* __restrict__ b2, const float* __restrict__ b3,
    const float* __restrict__ h_init,
    float* __restrict__ xw, float* __restrict__ leafC) {
  int id = blockIdx.x * 256 + threadIdx.x;
  if (id < 16384) {
    int op = id >> 12, g = (id >> 10) & 3, j = id & 1023;
    const float* wsrc; const float* bs;
    switch (g) {
      case 0: wsrc = w0; bs = b0; break;
      case 1: wsrc = w1; bs = b1; break;
      case 2: wsrc = w2; bs = b2; break;
      default: wsrc = w3; bs = b3; break;
    }
    const f4* xr = (const f4*)(op_emb + (size_t)op * 1024);
    const f4* wr = (const f4*)(wsrc + (size_t)j * 1024);
    float s = bs[j];
    for (int k = 0; k < 256; ++k) {
      f4 a = xr[k], b = wr[k];
      s += a[0] * b[0] + a[1] * b[1] + a[2] * b[2] + a[3] * b[3];
    }
    xw[id] = s;
  } else if (id < 21504) {
    int id2 = id - 16384;
    int sel = id2 >> 10, j = id2 & 1023;
    const f4* h0 = (const f4*)h_init;
    const f4* h1 = (const f4*)(h_init + 1024);
    float s;
    if (sel < 3) {
      const float* usrc; const float* bs;
      switch (sel) {
        case 0: usrc = u0; bs = b0; break;
        case 1: usrc = u1; bs = b1; break;
        default: usrc = u2; bs = b2; break;
      }
      const f4* wr = (const f4*)(usrc + (size_t)j * 1024);
      s = bs[j];
      for (int k = 0; k < 256; ++k) {
        f4 a0 = h0[k], a1 = h1[k], b = wr[k];
        s += (a0[0] + a1[0]) * b[0] + (a0[1] + a1[1]) * b[1] +
             (a0[2] + a1[2]) * b[2] + (a0[3] + a1[3]) * b[3];
      }
    } else {
      const f4* hs = (sel == 3) ? h0 : h1;
      const f4* wr = (const f4*)(u3 + (size_t)j * 1024);
      s = b3[j];
      for (int k = 0; k < 256; ++k) {
        f4 a = hs[k], b = wr[k];
        s += a[0] * b[0] + a[1] * b[1] + a[2] * b[2] + a[3] * b[3];
      }
    }
    leafC[id2] = s;
  }
}

// ---------------------------------------------------------------------------
// Main fused GEMM + TreeLSTM node kernel.
// Block: 256 thr = 4 waves. Tile: 64 A-rows x 64 cols x 4 gates (wave = gate).
// A [nrows][1024] bf16 (leaf tokens or child h), Wm [4][1024][1024] bf16.
// K-loop: BK=64 chunks staged via global_load_lds(16B) with XOR granule
// swizzle: granule (row,q) stored at row*8 + (q ^ (row&7)).
// MFMA 16x16x32 bf16: A frag m=lane&15,k=(lane>>4)*8+j; B frag n=lane&15 (B^T
// rows); C/D row=(lane>>4)*4+reg, col=lane&15  [m89/m91-verified layouts].
// Epilogue: gate tiles exchanged via LDS (bf16, stride 66), activations fused,
// writes c fp32 / h bf16 (or d_out at root).
// ---------------------------------------------------------------------------
__global__ __launch_bounds__(256) void tree_gemm(
    const u16* __restrict__ A, const u16* __restrict__ Wm,
    const float* __restrict__ consts,   // leafC[5][1024] or xw[4][4][1024]
    const int* __restrict__ ops,        // nullptr for leaf
    const float* __restrict__ c_in,     // c_init[2][1024] or child c [nrows][1024]
    float* __restrict__ c_out, u16* __restrict__ h_out,
    int nrows, int m_parents, int is_leaf, float* __restrict__ out_root) {
  __shared__ __align__(16) u16 smem[20480];  // 40960 B: A 8KB | B 4x8KB ; P aliased
  char* smem_c = (char*)smem;

  const int tid = threadIdx.x;
  const int wave = tid >> 6;
  const int lane = tid & 63;
  const int r0 = blockIdx.x * 64;
  const int j0 = blockIdx.y * 64;
  const int lrow8 = lane >> 3, ln7 = lane & 7;
  const int ln15 = lane & 15, quad = lane >> 4;

  // staging source byte offsets (advance 128 B per K-chunk)
  unsigned a_off[2];
#pragma unroll
  for (int t = 0; t < 2; ++t) {
    int idx = wave + t * 4;
    int row_l = idx * 8 + lrow8;              // stored row
    int q = ln7 ^ (row_l & 7);                // logical k-granule
    int grow = r0 + row_l; if (grow >= nrows) grow = nrows - 1;
    a_off[t] = ((unsigned)grow * 1024 + q * 8) * 2;
  }
  unsigned b_off[8];
#pragma unroll
  for (int t = 0; t < 8; ++t) {
    int row_l = t * 8 + lrow8;
    int q = ln7 ^ (row_l & 7);
    b_off[t] = ((unsigned)(wave * 1024 + j0 + row_l) * 1024 + q * 8) * 2;
  }

  // LDS read addresses for fragments (constant across chunks)
  unsigned a_rd[4][2], b_rd[4][2];
#pragma unroll
  for (int ri = 0; ri < 4; ++ri) {
    int row_l = ri * 16 + ln15;
#pragma unroll
    for (int ks = 0; ks < 2; ++ks) {
      int ql = ks * 4 + quad;
      a_rd[ri][ks] = (unsigned)(row_l * 8 + (ql ^ (row_l & 7))) * 16;
      b_rd[ri][ks] = 8192 + wave * 8192 + a_rd[ri][ks];
    }
  }

  f32x4 acc[4][4];
#pragma unroll
  for (int ri = 0; ri < 4; ++ri)
#pragma unroll
    for (int fj = 0; fj < 4; ++fj) acc[ri][fj] = (f32x4){0.f, 0.f, 0.f, 0.f};

  const char* Abase = (const char*)A;
  const char* Wbase = (const char*)Wm;

  for (int ch = 0; ch < 16; ++ch) {
    __syncthreads();  // previous chunk's ds_reads done before overwrite
    const unsigned chb = (unsigned)ch * 128;
#pragma unroll
    for (int t = 0; t < 2; ++t)
      __builtin_amdgcn_global_load_lds(
          (const __attribute__((address_space(1))) void*)(Abase + a_off[t] + chb),
          (__attribute__((address_space(3))) void*)(smem_c + (wave + t * 4) * 1024),
          16, 0, 0);
#pragma unroll
    for (int t = 0; t < 8; ++t)
      __builtin_amdgcn_global_load_lds(
          (const __attribute__((address_space(1))) void*)(Wbase + b_off[t] + chb),
          (__attribute__((address_space(3))) void*)(smem_c + 8192 + wave * 8192 + t * 1024),
          16, 0, 0);
    __syncthreads();  // drains vmcnt: staged data visible
#pragma unroll
    for (int ks = 0; ks < 2; ++ks) {
      bf16x8 af[4], bfr[4];
#pragma unroll
      for (int ri = 0; ri < 4; ++ri) af[ri] = *(const bf16x8*)(smem_c + a_rd[ri][ks]);
#pragma unroll
      for (int fj = 0; fj < 4; ++fj) bfr[fj] = *(const bf16x8*)(smem_c + b_rd[fj][ks]);
#pragma unroll
      for (int ri = 0; ri < 4; ++ri)
#pragma unroll
        for (int fj = 0; fj < 4; ++fj)
          acc[ri][fj] = __builtin_amdgcn_mfma_f32_16x16x32_bf16(af[ri], bfr[fj],
                                                                acc[ri][fj], 0, 0, 0);
    }
  }

  // ---- epilogue: exchange gate tiles through LDS (bf16, stride 66) ----
  __syncthreads();
#pragma unroll
  for (int ri = 0; ri < 4; ++ri)
#pragma unroll
    for (int fj = 0; fj < 4; ++fj)
#pragma unroll
      for (int k = 0; k < 4; ++k) {
        int row = ri * 16 + quad * 4 + k;
        int col = fj * 16 + ln15;
        smem[(wave * 64 + row) * 66 + col] = f2bf(acc[ri][fj][k]);
      }
  __syncthreads();

  if (is_leaf) {
    for (int e = tid; e < 4096; e += 256) {
      int r = e >> 6, j = e & 63;
      int col = j0 + j, n = r0 + r;
      float p0 = b2f(smem[(0 * 64 + r) * 66 + j]);
      float p1 = b2f(smem[(1 * 64 + r) * 66 + j]);
      float p2 = b2f(smem[(2 * 64 + r) * 66 + j]);
      float p3 = b2f(smem[(3 * 64 + r) * 66 + j]);
      float i_ = sigm(p0 + consts[col]);
      float o_ = sigm(p1 + consts[1024 + col]);
      float u_ = tanhf_(p2 + consts[2048 + col]);
      float f0 = sigm(p3 + consts[3072 + col]);
      float f1 = sigm(p3 + consts[4096 + col]);
      float c = i_ * u_ + f0 * c_in[col] + f1 * c_in[1024 + col];
      float h = o_ * tanhf_(c);
      c_out[(size_t)n * 1024 + col] = c;
      h_out[(size_t)n * 1024 + col] = f2bf(h);
    }
  } else {
    for (int e = tid; e < 2048; e += 256) {
      int p = e >> 6, j = e & 63;
      int np = (r0 >> 1) + p;
      if (np >= m_parents) break;  // p monotone in e per thread
      int col = j0 + j;
      int op = ops[np];
      const float* xwop = consts + ((unsigned)(op * 4) << 10);
      float p0a = b2f(smem[(0 * 64 + 2 * p) * 66 + j]), p0b = b2f(smem[(0 * 64 + 2 * p + 1) * 66 + j]);
      float p1a = b2f(smem[(1 * 64 + 2 * p) * 66 + j]), p1b = b2f(smem[(1 * 64 + 2 * p + 1) * 66 + j]);
      float p2a = b2f(smem[(2 * 64 + 2 * p) * 66 + j]), p2b = b2f(smem[(2 * 64 + 2 * p + 1) * 66 + j]);
      float p3a = b2f(smem[(3 * 64 + 2 * p) * 66 + j]), p3b = b2f(smem[(3 * 64 + 2 * p + 1) * 66 + j]);
      float i_ = sigm(p0a + p0b + xwop[col]);
      float o_ = sigm(p1a + p1b + xwop[1024 + col]);
      float u_ = tanhf_(p2a + p2b + xwop[2048 + col]);
      float f0 = sigm(p3a + xwop[3072 + col]);
      float f1 = sigm(p3b + xwop[3072 + col]);
      float c = i_ * u_ + f0 * c_in[(size_t)(r0 + 2 * p) * 1024 + col]
                        + f1 * c_in[(size_t)(r0 + 2 * p + 1) * 1024 + col];
      float h = o_ * tanhf_(c);
      if (m_parents == 1) {
        out_root[col] = c;
        out_root[1024 + col] = h;
      } else {
        c_out[(size_t)np * 1024 + col] = c;
        h_out[(size_t)np * 1024 + col] = f2bf(h);
      }
    }
  }
}

// ---------------------------------------------------------------------------
extern "C" void kernel_launch(void* const* d_in, const int* in_sizes, int n_in,
                              void* d_out, int out_size, void* d_ws, size_t ws_size,
                              hipStream_t stream) {
  const float* tokens = (const float*)d_in[0];
  const int* leaf_ids = (const int*)d_in[1];
  const int* op_ids = (const int*)d_in[2];
  const float* W0 = (const float*)d_in[3];
  const float* W1 = (const float*)d_in[4];
  const float* W2 = (const float*)d_in[5];
  const float* W3 = (const float*)d_in[6];
  const float* U0 = (const float*)d_in[7];
  const float* U1 = (const float*)d_in[8];
  const float* U2 = (const float*)d_in[9];
  const float* U3 = (const float*)d_in[10];
  const float* B0 = (const float*)d_in[11];
  const float* B1 = (const float*)d_in[12];
  const float* B2 = (const float*)d_in[13];
  const float* B3 = (const float*)d_in[14];
  const float* op_emb = (const float*)d_in[15];
  const float* c_init = (const float*)d_in[16];
  const float* h_init = (const float*)d_in[17];
  float* out = (float*)d_out;

  // workspace layout (~104 MB)
  char* ws = (char*)d_ws;
  u16* Wb = (u16*)ws;                                  // 4M u16  (8 MB)
  u16* Ub = Wb + (size_t)4 * 1024 * 1024;              // 4M u16  (8 MB)
  u16* Xl = Ub + (size_t)4 * 1024 * 1024;              // 8M u16  (16 MB)
  u16* hA = Xl + (size_t)8192 * 1024;                  // 8M u16  (16 MB)
  u16* hB = hA + (size_t)8192 * 1024;                  // 4M u16  (8 MB)
  float* cA = (float*)(hB + (size_t)4096 * 1024);      // 8M f32  (32 MB)
  float* cB = cA + (size_t)8192 * 1024;                // 4M f32  (16 MB)
  float* xw = cB + (size_t)4096 * 1024;                // 16K f32
  float* lc = xw + 16 * 1024;                          // 5K f32

  convert_wu_kernel<<<8192, 256, 0, stream>>>(W0, W1, W2, W3, U0, U1, U2, U3, Wb, Ub);
  gather_leaf_kernel<<<8192, 256, 0, stream>>>(tokens, leaf_ids, Xl);
  precompute_kernel<<<84, 256, 0, stream>>>(op_emb, W0, W1, W2, W3, U0, U1, U2, U3,
                                            B0, B1, B2, B3, h_init, xw, lc);

  // leaves: 8192 rows
  tree_gemm<<<dim3(128, 16), 256, 0, stream>>>(Xl, Wb, lc, nullptr, c_init,
                                               cA, hA, 8192, 0, 1, out);

  const u16* hin = hA; const float* cin = cA;
  u16* hout = hB; float* cout = cB;
  for (int l = 12; l >= 0; --l) {
    int m = 1 << l;
    int rb = (2 * m) / 64; if (rb < 1) rb = 1;
    tree_gemm<<<dim3(rb, 16), 256, 0, stream>>>(hin, Ub, xw, op_ids + (m - 1), cin,
                                                cout, hout, 2 * m, m, 0, out);
    const u16* th = hin; hin = hout; hout = (u16*)th;
    const float* tc = cin; cin = cout; cout = (float*)tc;
  }
}